// Round 4
// baseline (246.785 us; speedup 1.0000x reference)
//
#include <hip/hip_runtime.h>
#include <cstdint>
#include <cstddef>

// ---------------- types ----------------
typedef __attribute__((ext_vector_type(4))) float  floatx4;
typedef __attribute__((ext_vector_type(8))) __bf16 bf16x8;
typedef __attribute__((ext_vector_type(8))) unsigned short u16x8;

#define M_TOT 16384   // B*S
#define N_TOT 2048    // D_OUT
#define K_TOT 2048    // D_IN
#define NBATCH 8
#define RLORA 16
#define NT 32         // K tiles of 64

// f32 -> bf16 round-to-nearest-even
__device__ __forceinline__ unsigned short f32_to_bf16(float f) {
  unsigned u = __float_as_uint(f);
  u += 0x7fffu + ((u >> 16) & 1u);
  return (unsigned short)(u >> 16);
}

__device__ __forceinline__ u16x8 cvt8(const float4& a, const float4& b) {
  u16x8 o;
  o[0] = f32_to_bf16(a.x); o[1] = f32_to_bf16(a.y);
  o[2] = f32_to_bf16(a.z); o[3] = f32_to_bf16(a.w);
  o[4] = f32_to_bf16(b.x); o[5] = f32_to_bf16(b.y);
  o[6] = f32_to_bf16(b.z); o[7] = f32_to_bf16(b.w);
  return o;
}

// async global->LDS, 16B per lane (LDS dest wave-uniform base + lane*16)
#define GLOAD_LDS16(gp, lp)                                                        \
  __builtin_amdgcn_global_load_lds((__attribute__((address_space(1))) void*)(void*)(gp), \
                                   (__attribute__((address_space(3))) void*)(void*)(lp), \
                                   16, 0, 0)

template<int V> struct IC { static constexpr int value = V; };

// ---------------- elementwise f32 -> bf16 (8 elems/thread) ----------------
__global__ void k_convert(const float* __restrict__ in, unsigned short* __restrict__ out, int n8) {
  int i = blockIdx.x * blockDim.x + threadIdx.x;
  if (i >= n8) return;
  const float4* p = (const float4*)in + (size_t)i * 2;
  *(u16x8*)(out + (size_t)i * 8) = cvt8(p[0], p[1]);
}

// ---------------- A_params [8][2048][16] f32 -> [8*2048][32] bf16, zero-padded ----------------
__global__ void k_convert_a(const float* __restrict__ A, unsigned short* __restrict__ abf) {
  int row = blockIdx.x * blockDim.x + threadIdx.x;
  if (row >= NBATCH * N_TOT) return;
  const float4* p = (const float4*)(A + (size_t)row * RLORA);
  u16x8 lo = cvt8(p[0], p[1]), hi2 = cvt8(p[2], p[3]), z = {0,0,0,0,0,0,0,0};
  u16x8* dst = (u16x8*)(abf + (size_t)row * 32);
  dst[0] = lo; dst[1] = hi2; dst[2] = z; dst[3] = z;
}

// ---------------- fused: xbf = bf16(x); inter[m][r] = sum_i xbf[m][i]*bf16(Bp)[b][r][i] ----------------
__global__ __launch_bounds__(256) void k_inter(const float* __restrict__ x,
                                               const float* __restrict__ Bp,
                                               unsigned short* __restrict__ xbf,
                                               unsigned short* __restrict__ interbf) {
  const int tid  = threadIdx.x;
  const int lane = tid & 63;
  const int wv   = tid >> 6;
  const int l15  = lane & 15;
  const int hi   = lane >> 4;
  const int m0   = blockIdx.x * 64;
  const int bb   = m0 >> 11;

  floatx4 zero = {0.f, 0.f, 0.f, 0.f};
  floatx4 acc[4] = {zero, zero, zero, zero};

  const float* bpb = Bp + (size_t)bb * (RLORA * K_TOT);
  const int kb0 = wv * 512;
  for (int kb = kb0; kb < kb0 + 512; kb += 32) {
    const float* bp = bpb + (size_t)l15 * K_TOT + kb + hi * 8;
    u16x8 bo = cvt8(*(const float4*)bp, *(const float4*)(bp + 4));
    bf16x8 bfr = *(bf16x8*)&bo;
    #pragma unroll
    for (int mi = 0; mi < 4; ++mi) {
      size_t off = (size_t)(m0 + mi * 16 + l15) * K_TOT + kb + hi * 8;
      const float* xp = x + off;
      u16x8 ao = cvt8(*(const float4*)xp, *(const float4*)(xp + 4));
      *(u16x8*)(xbf + off) = ao;
      acc[mi] = __builtin_amdgcn_mfma_f32_16x16x32_bf16(*(bf16x8*)&ao, bfr, acc[mi], 0, 0, 0);
    }
  }

  __shared__ floatx4 red[4][4][64];
  #pragma unroll
  for (int mi = 0; mi < 4; ++mi) red[wv][mi][lane] = acc[mi];
  __syncthreads();
  if (wv == 0) {
    #pragma unroll
    for (int mi = 0; mi < 4; ++mi) {
      floatx4 s = red[0][mi][lane] + red[1][mi][lane] + red[2][mi][lane] + red[3][mi][lane];
      #pragma unroll
      for (int j = 0; j < 4; ++j) {
        int m = m0 + mi * 16 + hi * 4 + j;
        interbf[(size_t)m * 32 + l15] = f32_to_bf16(s[j]);
        interbf[(size_t)m * 32 + 16 + l15] = 0;
      }
    }
  }
}

// ---------------- main GEMM: 256x256, BK=64, 8 waves, balanced 8-phase pipeline ----------------
// Even schedule (per tile τ, reading buf=τ&1; snake Q00,Q01,Q11,Q10):
//   P1: read bfS=B(τ)qn1[4];   stage A1(τ+1);              lgkm(4);  MFMA Q00(afA,bfF)
//   P2: read afB=A(τ)qm1[8];   stage B0(τ+2);              lgkm(8);  MFMA Q01(afA,bfS)
//   P3: vmcnt(6); read bfN=B(τ+1)qn0[4]; stage B1(τ+2);    lgkm(4);  MFMA Q11(afB,bfS)
//   P4: vmcnt(4); read afA=A(τ+1)qm0[8]; stage A0(τ+2);    no lgkm;  MFMA Q10(afB,bfF)
// Death-order verified: every staged half is ≥1 full phase dead for all waves; every
// consumer read is covered by the preceding counted vmcnt; vmcnt never 0 until peel.
#define STAGE_A(bufi, h, tt) do {                                                      \
  GLOAD_LDS16(Ag + (h)*262144 + (tt)*64 + gOff0, AsB + ((bufi)*2+(h))*16384 + ldsB0);  \
  GLOAD_LDS16(Ag + (h)*262144 + (tt)*64 + gOff1, AsB + ((bufi)*2+(h))*16384 + ldsB1);  \
} while(0)
#define STAGE_B(bufi, h, tt) do {                                                      \
  GLOAD_LDS16(Bg + (h)*262144 + (tt)*64 + gOff0, BsB + ((bufi)*2+(h))*16384 + ldsB0);  \
  GLOAD_LDS16(Bg + (h)*262144 + (tt)*64 + gOff1, BsB + ((bufi)*2+(h))*16384 + ldsB1);  \
} while(0)
#define RDA_(B2, qm, mi, ks) (*(const bf16x8*)(AsB + (B2)*32768 + aBase + (qm)*8192 + (mi)*2048 + koff[ks]))
#define RDB_(B2, ni, ks)     (*(const bf16x8*)(BsB + (B2)*32768 + bBase + (ni)*2048 + koff[ks]))
#define BAR() __builtin_amdgcn_s_barrier()
#define MFMA16(MB, NB, AF, BF) do {                                                        \
  _Pragma("unroll")                                                                        \
  for (int mi = 0; mi < 4; ++mi) {                                                         \
    _Pragma("unroll")                                                                      \
    for (int j = 0; j < 2; ++j) {                                                          \
      acc[(MB)+mi][(NB)+j] = __builtin_amdgcn_mfma_f32_16x16x32_bf16(AF[mi][0], BF[j][0], acc[(MB)+mi][(NB)+j], 0, 0, 0); \
      acc[(MB)+mi][(NB)+j] = __builtin_amdgcn_mfma_f32_16x16x32_bf16(AF[mi][1], BF[j][1], acc[(MB)+mi][(NB)+j], 0, 0, 0); \
    }                                                                                      \
  }                                                                                        \
} while(0)

__global__ __launch_bounds__(512, 2) void k_gemm(const unsigned short* __restrict__ xbf,
                                                 const unsigned short* __restrict__ wbf,
                                                 const unsigned short* __restrict__ interbf,
                                                 const unsigned short* __restrict__ abf,
                                                 const float* __restrict__ bias,
                                                 float* __restrict__ out) {
  __shared__ unsigned short As[2][2][8192];
  __shared__ unsigned short Bs[2][2][8192];
  const int tid  = threadIdx.x;
  const int lane = tid & 63;
  const int wid  = tid >> 6;     // 0..7
  const int wm   = wid >> 2;     // 0..1
  const int wn   = wid & 3;      // 0..3
  const int l15  = lane & 15;
  const int hi   = lane >> 4;
  const int swz  = l15 & 7;

  // XCD-aware bijective swizzle: grid 512 = 64 mt x 8 nt
  int bid  = blockIdx.x;
  int swzb = ((bid & 7) << 6) | (bid >> 3);
  const int mt = swzb >> 3;
  const int nt = swzb & 7;
  const int mrow0 = mt << 8;
  const int ncol0 = nt << 8;
  const int bb = mrow0 >> 11;

  const int m0 = mrow0 + wm * 128;
  const int n0 = ncol0 + wn * 64;

  const unsigned short* Ag = xbf + (size_t)mrow0 * K_TOT;
  const unsigned short* Bg = wbf + (size_t)ncol0 * K_TOT;
  char* AsB = (char*)As;
  char* BsB = (char*)Bs;

  // staging offsets (pre-swizzled source; linear LDS dest)
  const int r0    = tid >> 3;
  const int k80   = (tid & 7) ^ (r0 & 7);
  const int gOff0 = r0 * K_TOT + k80 * 8;
  const int gOff1 = gOff0 + 64 * K_TOT;
  const int ldsB0 = wid * 1024;
  const int ldsB1 = 8192 + wid * 1024;

  // fragment read bases (byte offsets within As/Bs)
  const int aBase = wm * 16384 + l15 * 128;
  const int bBase = wn * 8192  + l15 * 128;
  int koff[2];
  koff[0] = ((0 * 4 + hi) ^ swz) * 16;
  koff[1] = ((1 * 4 + hi) ^ swz) * 16;

  floatx4 acc[8][4];
  bf16x8 afA[4][2], afB[4][2], bfS[2][2], bfP[2][2], bfQ[2][2];

  // ---- prologue: LoRA loads, stage 7 half-tiles, LoRA MFMA
  {
    bf16x8 la[8], lb[4];
    #pragma unroll
    for (int mi = 0; mi < 8; ++mi)
      la[mi] = *(const bf16x8*)(interbf + (size_t)(m0 + mi * 16 + l15) * 32 + hi * 8);
    #pragma unroll
    for (int ni = 0; ni < 4; ++ni)
      lb[ni] = *(const bf16x8*)(abf + ((size_t)bb * N_TOT + n0 + ni * 16 + l15) * 32 + hi * 8);

    STAGE_B(0, 0, 0); STAGE_B(0, 1, 0); STAGE_A(0, 0, 0); STAGE_A(0, 1, 0);
    STAGE_B(1, 0, 1); STAGE_B(1, 1, 1); STAGE_A(1, 0, 1);

    floatx4 z = {0.f, 0.f, 0.f, 0.f};
    #pragma unroll
    for (int mi = 0; mi < 8; ++mi)
      #pragma unroll
      for (int ni = 0; ni < 4; ++ni)
        acc[mi][ni] = __builtin_amdgcn_mfma_f32_16x16x32_bf16(la[mi], lb[ni], z, 0, 0, 0);
  }
  asm volatile("s_waitcnt vmcnt(6)" ::: "memory");   // tile0 landed; tile1 B0,B1,A0 in flight
  BAR();
  // pre-slot: tile0's afA (qm0) + bfP (qn0)
  #pragma unroll
  for (int mi = 0; mi < 4; ++mi) { afA[mi][0] = RDA_(0, 0, mi, 0); afA[mi][1] = RDA_(0, 0, mi, 1); }
  #pragma unroll
  for (int j = 0; j < 2; ++j)    { bfP[j][0]  = RDB_(0, j, 0);     bfP[j][1]  = RDB_(0, j, 1); }

  auto tile_step = [&](int t, auto bufc, auto s1c, auto s2c, auto vm3c, auto vm4c, auto lastc,
                       auto& bfF, auto& bfN) {
    constexpr int BUF  = decltype(bufc)::value;
    constexpr int S1   = decltype(s1c)::value;
    constexpr int S2   = decltype(s2c)::value;
    constexpr int VM3  = decltype(vm3c)::value;
    constexpr int VM4  = decltype(vm4c)::value;
    constexpr int LAST = decltype(lastc)::value;

    // ---- P1: slot bfS=B(τ)qn1; stage A1(τ+1)->BUF^1; MFMA Q00
    #pragma unroll
    for (int j = 0; j < 2; ++j) { bfS[j][0] = RDB_(BUF, 2 + j, 0); bfS[j][1] = RDB_(BUF, 2 + j, 1); }
    if constexpr (S1) STAGE_A(BUF ^ 1, 1, t + 1);
    BAR();
    asm volatile("s_waitcnt lgkmcnt(4)" ::: "memory");
    __builtin_amdgcn_s_setprio(1);
    MFMA16(0, 0, afA, bfF);
    __builtin_amdgcn_s_setprio(0);
    BAR();

    // ---- P2: slot afB=A(τ)qm1; stage B0(τ+2)->BUF; MFMA Q01
    #pragma unroll
    for (int mi = 0; mi < 4; ++mi) { afB[mi][0] = RDA_(BUF, 1, mi, 0); afB[mi][1] = RDA_(BUF, 1, mi, 1); }
    if constexpr (S2) STAGE_B(BUF, 0, t + 2);
    BAR();
    asm volatile("s_waitcnt lgkmcnt(8)" ::: "memory");
    __builtin_amdgcn_s_setprio(1);
    MFMA16(0, 2, afA, bfS);
    __builtin_amdgcn_s_setprio(0);
    BAR();

    // ---- P3: vmcnt; slot bfN=B(τ+1)qn0; stage B1(τ+2)->BUF; MFMA Q11
    if constexpr (VM3 >= 0) {
      if constexpr (VM3 == 6)      asm volatile("s_waitcnt vmcnt(6)" ::: "memory");
      else if constexpr (VM3 == 4) asm volatile("s_waitcnt vmcnt(4)" ::: "memory");
      else                         asm volatile("s_waitcnt vmcnt(0)" ::: "memory");
    }
    if constexpr (!LAST) {
      #pragma unroll
      for (int j = 0; j < 2; ++j) { bfN[j][0] = RDB_(BUF ^ 1, j, 0); bfN[j][1] = RDB_(BUF ^ 1, j, 1); }
    }
    if constexpr (S2) STAGE_B(BUF, 1, t + 2);
    BAR();
    if constexpr (LAST) asm volatile("s_waitcnt lgkmcnt(0)" ::: "memory");
    else                asm volatile("s_waitcnt lgkmcnt(4)" ::: "memory");
    __builtin_amdgcn_s_setprio(1);
    MFMA16(4, 2, afB, bfS);
    __builtin_amdgcn_s_setprio(0);
    BAR();

    // ---- P4: vmcnt; slot afA=A(τ+1)qm0; stage A0(τ+2)->BUF; MFMA Q10 (no lgkm wait)
    if constexpr (VM4 >= 0) {
      if constexpr (VM4 == 4) asm volatile("s_waitcnt vmcnt(4)" ::: "memory");
      else                    asm volatile("s_waitcnt vmcnt(0)" ::: "memory");
    }
    if constexpr (!LAST) {
      #pragma unroll
      for (int mi = 0; mi < 4; ++mi) { afA[mi][0] = RDA_(BUF ^ 1, 0, mi, 0); afA[mi][1] = RDA_(BUF ^ 1, 0, mi, 1); }
    }
    if constexpr (S2) STAGE_A(BUF, 0, t + 2);
    BAR();
    __builtin_amdgcn_s_setprio(1);
    MFMA16(4, 0, afB, bfF);
    __builtin_amdgcn_s_setprio(0);
    BAR();
  };

  for (int t = 0; t < NT - 2; t += 2) {
    tile_step(t,     IC<0>{}, IC<1>{}, IC<1>{}, IC<6>{}, IC<4>{}, IC<0>{}, bfP, bfQ);
    tile_step(t + 1, IC<1>{}, IC<1>{}, IC<1>{}, IC<6>{}, IC<4>{}, IC<0>{}, bfQ, bfP);
  }
  tile_step(NT - 2, IC<0>{}, IC<1>{}, IC<0>{}, IC<4>{}, IC<0>{},  IC<0>{}, bfP, bfQ);
  tile_step(NT - 1, IC<1>{}, IC<0>{}, IC<0>{}, IC<-1>{}, IC<-1>{}, IC<1>{}, bfQ, bfP);

  // ---- epilogue: + bias, store f32 ----
  #pragma unroll
  for (int ni = 0; ni < 4; ++ni) {
    int col = n0 + ni * 16 + l15;
    float bv = bias[col];
    #pragma unroll
    for (int mi = 0; mi < 8; ++mi) {
      int r = m0 + mi * 16 + hi * 4;
      #pragma unroll
      for (int j = 0; j < 4; ++j)
        out[(size_t)(r + j) * N_TOT + col] = acc[mi][ni][j] + bv;
    }
  }
}

// ---------------- launcher ----------------
extern "C" void kernel_launch(void* const* d_in, const int* in_sizes, int n_in,
                              void* d_out, int out_size, void* d_ws, size_t ws_size,
                              hipStream_t stream) {
  const float* x    = (const float*)d_in[0];
  const float* Ap   = (const float*)d_in[1];
  const float* Bp   = (const float*)d_in[2];
  const float* W    = (const float*)d_in[3];
  const float* bias = (const float*)d_in[4];
  float* out = (float*)d_out;

  char* ws = (char*)d_ws;
  unsigned short* xbf     = (unsigned short*)(ws);                        // 64 MiB
  unsigned short* wbf     = (unsigned short*)(ws + 67108864);             // 8 MiB
  unsigned short* abf     = (unsigned short*)(ws + 67108864 + 8388608);   // 1 MiB
  unsigned short* interbf = (unsigned short*)(ws + 67108864 + 8388608 + 1048576); // 1 MiB

  k_convert<<<dim3(2048),  dim3(256), 0, stream>>>(W,  wbf, 524288);
  k_convert_a<<<dim3(64),  dim3(256), 0, stream>>>(Ap, abf);

  // fused: x f32 -> xbf (bf16) + inter = x @ Bp^T
  k_inter<<<dim3(256), dim3(256), 0, stream>>>(x, Bp, xbf, interbf);

  k_gemm<<<dim3(512), dim3(512), 0, stream>>>(xbf, wbf, interbf, abf, bias, out);
}

// Round 5
// 223.679 us; speedup vs baseline: 1.1033x; 1.1033x over previous
//
#include <hip/hip_runtime.h>
#include <cstdint>
#include <cstddef>

// ---------------- types ----------------
typedef __attribute__((ext_vector_type(4))) float  floatx4;
typedef __attribute__((ext_vector_type(8))) __bf16 bf16x8;
typedef __attribute__((ext_vector_type(8))) unsigned short u16x8;

#define M_TOT 16384   // B*S
#define N_TOT 2048    // D_OUT
#define K_TOT 2048    // D_IN
#define NBATCH 8
#define RLORA 16

// f32 -> bf16 round-to-nearest-even
__device__ __forceinline__ unsigned short f32_to_bf16(float f) {
  unsigned u = __float_as_uint(f);
  u += 0x7fffu + ((u >> 16) & 1u);
  return (unsigned short)(u >> 16);
}

__device__ __forceinline__ u16x8 cvt8(const float4& a, const float4& b) {
  u16x8 o;
  o[0] = f32_to_bf16(a.x); o[1] = f32_to_bf16(a.y);
  o[2] = f32_to_bf16(a.z); o[3] = f32_to_bf16(a.w);
  o[4] = f32_to_bf16(b.x); o[5] = f32_to_bf16(b.y);
  o[6] = f32_to_bf16(b.z); o[7] = f32_to_bf16(b.w);
  return o;
}

// async global->LDS, 16B per lane (LDS dest wave-uniform base + lane*16)
#define GLOAD_LDS16(gp, lp)                                                        \
  __builtin_amdgcn_global_load_lds((__attribute__((address_space(1))) void*)(void*)(gp), \
                                   (__attribute__((address_space(3))) void*)(void*)(lp), \
                                   16, 0, 0)

// ---------------- x convert: grid-stride, 2048 blocks x 256 thr, 8 units of 8 elems ----------------
__global__ void k_convert_x(const float* __restrict__ in, unsigned short* __restrict__ out) {
  int i0 = blockIdx.x * blockDim.x + threadIdx.x;          // 0..524287
  #pragma unroll
  for (int it = 0; it < 8; ++it) {
    size_t i = (size_t)i0 + (size_t)it * 524288;           // 4194304 units total
    const float4* p = (const float4*)in + i * 2;
    *(u16x8*)(out + i * 8) = cvt8(p[0], p[1]);
  }
}

// ---------------- combined small converts: W (2048 blocks) | Bp (128) | A_params pack (64) ----------------
__global__ void k_convert_small(const float* __restrict__ W, const float* __restrict__ Bp,
                                const float* __restrict__ Ap,
                                unsigned short* __restrict__ wbf, unsigned short* __restrict__ bpbf,
                                unsigned short* __restrict__ abf) {
  int b = blockIdx.x;
  if (b < 2048) {                       // W: 4.19M elems = 524288 8-elem units
    int i = b * 256 + threadIdx.x;
    const float4* p = (const float4*)W + (size_t)i * 2;
    *(u16x8*)(wbf + (size_t)i * 8) = cvt8(p[0], p[1]);
  } else if (b < 2176) {                // Bp: 262144 elems = 32768 units
    int i = (b - 2048) * 256 + threadIdx.x;
    const float4* p = (const float4*)Bp + (size_t)i * 2;
    *(u16x8*)(bpbf + (size_t)i * 8) = cvt8(p[0], p[1]);
  } else {                              // A_params: [8*2048][16] -> [8*2048][32] zero-padded
    int row = (b - 2176) * 256 + threadIdx.x;
    const float4* p = (const float4*)(Ap + (size_t)row * RLORA);
    u16x8 lo = cvt8(p[0], p[1]), hi2 = cvt8(p[2], p[3]), z = {0,0,0,0,0,0,0,0};
    u16x8* dst = (u16x8*)(abf + (size_t)row * 32);
    dst[0] = lo; dst[1] = hi2; dst[2] = z; dst[3] = z;
  }
}

// ---------------- fused GEMM: out = x@W^T + b + (x@Bp^T)@Ap^T ----------------
// R1-verified 128x128 core (2-barrier, gload_lds, chunk^=(row&7) swizzle, 0 conflicts).
// NEW: inter = x@Bp^T computed IN the K-loop (reusing A-frags; wn-split of mi rows, +4 MFMA/K-tile),
// LoRA adaptation applied in epilogue via 16 MFMAs (interL in LDS aliasing As, dead after K-loop).
__global__ __launch_bounds__(256) void k_gemm(const unsigned short* __restrict__ xbf,
                                              const unsigned short* __restrict__ wbf,
                                              const unsigned short* __restrict__ bpbf,
                                              const unsigned short* __restrict__ abf,
                                              const float* __restrict__ bias,
                                              float* __restrict__ out) {
  __shared__ unsigned short As[128 * 64];
  __shared__ unsigned short Bs[128 * 64];
  __shared__ unsigned short BpL[16 * 64];
  const int tid  = threadIdx.x;
  const int lane = tid & 63;
  const int wv   = tid >> 6;
  const int wm   = wv >> 1, wn = wv & 1;
  const int l15  = lane & 15;
  const int hi   = lane >> 4;
  const int swz  = l15 & 7;

  // XCD-aware bijective swizzle (grid = 2048, 2048 % 8 == 0)
  int bid  = blockIdx.x;
  int swzb = ((bid & 7) << 8) | (bid >> 3);
  const int mt = swzb >> 4;
  const int nt = swzb & 15;
  const int mrow0 = mt << 7;
  const int ncol0 = nt << 7;
  const int bb = mrow0 >> 11;           // batch (128 | 2048)

  const int m0 = mrow0 + wm * 64;
  const int n0 = ncol0 + wn * 64;

  // ---- staging pointers (pre-swizzled source, linear LDS dest)
  const unsigned short* Ag  = xbf  + (size_t)mrow0 * K_TOT;
  const unsigned short* Bg  = wbf  + (size_t)ncol0 * K_TOT;
  const unsigned short* Bpg = bpbf + (size_t)bb * (RLORA * K_TOT);
  const unsigned short* pA[4];
  const unsigned short* pB[4];
  int ldsOff[4];
  #pragma unroll
  for (int i = 0; i < 4; ++i) {
    int c   = i * 256 + wv * 64 + lane;
    int row = c >> 3;
    int k8  = (c & 7) ^ (row & 7);
    pA[i] = Ag + (size_t)row * K_TOT + k8 * 8;
    pB[i] = Bg + (size_t)row * K_TOT + k8 * 8;
    ldsOff[i] = (i * 256 + wv * 64) * 16;
  }
  // Bp staging offsets (valid for tid < 128; waves 0,1 issue)
  const int bpr   = tid >> 3;                               // 0..15 (over waves 0,1)
  const int bpOff = bpr * K_TOT + ((tid & 7) ^ (bpr & 7)) * 8;

  floatx4 zero = {0.f, 0.f, 0.f, 0.f};
  floatx4 acc[4][4];
  #pragma unroll
  for (int mi = 0; mi < 4; ++mi)
    #pragma unroll
    for (int ni = 0; ni < 4; ++ni) acc[mi][ni] = zero;
  floatx4 accI[2] = {zero, zero};

  for (int kt = 0; kt < K_TOT; kt += 64) {
    #pragma unroll
    for (int i = 0; i < 4; ++i) GLOAD_LDS16(pA[i] + kt, (char*)As + ldsOff[i]);
    #pragma unroll
    for (int i = 0; i < 4; ++i) GLOAD_LDS16(pB[i] + kt, (char*)Bs + ldsOff[i]);
    if (wv < 2) GLOAD_LDS16(Bpg + kt + bpOff, (char*)BpL + wv * 1024);
    asm volatile("s_waitcnt vmcnt(0)" ::: "memory");
    __syncthreads();

    #pragma unroll
    for (int ks = 0; ks < 2; ++ks) {
      bf16x8 af[4], bfv[4];
      #pragma unroll
      for (int mi = 0; mi < 4; ++mi) {
        int row = wm * 64 + mi * 16 + l15;
        int k8  = (ks * 4 + hi) ^ (row & 7);
        af[mi] = *(const bf16x8*)((const char*)As + row * 128 + k8 * 16);
      }
      #pragma unroll
      for (int ni = 0; ni < 4; ++ni) {
        int row = wn * 64 + ni * 16 + l15;
        int k8  = (ks * 4 + hi) ^ (row & 7);
        bfv[ni] = *(const bf16x8*)((const char*)Bs + row * 128 + k8 * 16);
      }
      bf16x8 bpf = *(const bf16x8*)((const char*)BpL + l15 * 128 + (((ks * 4 + hi) ^ swz) * 16));
      #pragma unroll
      for (int mi = 0; mi < 4; ++mi)
        #pragma unroll
        for (int ni = 0; ni < 4; ++ni)
          acc[mi][ni] = __builtin_amdgcn_mfma_f32_16x16x32_bf16(af[mi], bfv[ni], acc[mi][ni], 0, 0, 0);
      // inter = x @ Bp^T for this wave's mi pair (static indices; wn uniform branch)
      if (wn == 0) {
        accI[0] = __builtin_amdgcn_mfma_f32_16x16x32_bf16(af[0], bpf, accI[0], 0, 0, 0);
        accI[1] = __builtin_amdgcn_mfma_f32_16x16x32_bf16(af[1], bpf, accI[1], 0, 0, 0);
      } else {
        accI[0] = __builtin_amdgcn_mfma_f32_16x16x32_bf16(af[2], bpf, accI[0], 0, 0, 0);
        accI[1] = __builtin_amdgcn_mfma_f32_16x16x32_bf16(af[3], bpf, accI[1], 0, 0, 0);
      }
    }
    __syncthreads();
  }

  // ---- epilogue: LoRA adaptation via MFMA, then bias + store ----
  // prefetch Ap fragments (global) while LDS exchange happens
  bf16x8 lb[4];
  #pragma unroll
  for (int ni = 0; ni < 4; ++ni)
    lb[ni] = *(const bf16x8*)(abf + ((size_t)bb * N_TOT + n0 + ni * 16 + l15) * 32 + hi * 8);

  // interL[128][32] bf16 (zero-padded K=16..31), aliases As (dead after K-loop; last sync covers reads)
  unsigned short* interL = As;
  #pragma unroll
  for (int p = 0; p < 2; ++p) {
    #pragma unroll
    for (int j = 0; j < 4; ++j) {
      int row = wm * 64 + (2 * wn + p) * 16 + hi * 4 + j;   // C-layout: row=hi*4+j, col=l15=r
      interL[row * 32 + l15]      = f32_to_bf16(accI[p][j]);
      interL[row * 32 + 16 + l15] = 0;
    }
  }
  __syncthreads();

  bf16x8 la[4];
  #pragma unroll
  for (int mi = 0; mi < 4; ++mi)
    la[mi] = *(const bf16x8*)(interL + (wm * 64 + mi * 16 + l15) * 32 + hi * 8);
  #pragma unroll
  for (int mi = 0; mi < 4; ++mi)
    #pragma unroll
    for (int ni = 0; ni < 4; ++ni)
      acc[mi][ni] = __builtin_amdgcn_mfma_f32_16x16x32_bf16(la[mi], lb[ni], acc[mi][ni], 0, 0, 0);

  #pragma unroll
  for (int ni = 0; ni < 4; ++ni) {
    int col = n0 + ni * 16 + l15;
    float bv = bias[col];
    #pragma unroll
    for (int mi = 0; mi < 4; ++mi) {
      int r0 = m0 + mi * 16 + hi * 4;
      #pragma unroll
      for (int j = 0; j < 4; ++j)
        out[(size_t)(r0 + j) * N_TOT + col] = acc[mi][ni][j] + bv;
    }
  }
}

// ---------------- launcher ----------------
extern "C" void kernel_launch(void* const* d_in, const int* in_sizes, int n_in,
                              void* d_out, int out_size, void* d_ws, size_t ws_size,
                              hipStream_t stream) {
  const float* x    = (const float*)d_in[0];   // [8,2048,2048]
  const float* Ap   = (const float*)d_in[1];   // [8,2048,16]
  const float* Bp   = (const float*)d_in[2];   // [8,16,2048]
  const float* W    = (const float*)d_in[3];   // [2048,2048]
  const float* bias = (const float*)d_in[4];   // [2048]
  float* out = (float*)d_out;

  char* ws = (char*)d_ws;
  unsigned short* xbf  = (unsigned short*)(ws);                       // 64 MiB
  unsigned short* wbf  = (unsigned short*)(ws + 67108864);            // 8 MiB
  unsigned short* abf  = (unsigned short*)(ws + 67108864 + 8388608);  // 1 MiB
  unsigned short* bpbf = (unsigned short*)(ws + 67108864 + 8388608 + 1048576); // 0.5 MiB

  k_convert_small<<<dim3(2240), dim3(256), 0, stream>>>(W, Bp, Ap, wbf, bpbf, abf);
  k_convert_x<<<dim3(2048), dim3(256), 0, stream>>>(x, xbf);
  k_gemm<<<dim3(2048), dim3(256), 0, stream>>>(xbf, wbf, bpbf, abf, bias, out);
}

// Round 6
// 197.605 us; speedup vs baseline: 1.2489x; 1.1319x over previous
//
#include <hip/hip_runtime.h>
#include <cstdint>
#include <cstddef>

// ---------------- types ----------------
typedef __attribute__((ext_vector_type(4))) float  floatx4;
typedef __attribute__((ext_vector_type(8))) __bf16 bf16x8;
typedef __attribute__((ext_vector_type(8))) unsigned short u16x8;

#define M_TOT 16384   // B*S
#define N_TOT 2048    // D_OUT
#define K_TOT 2048    // D_IN
#define NBATCH 8
#define RLORA 16
#define NT 32         // K tiles of 64

// f32 -> bf16 round-to-nearest-even
__device__ __forceinline__ unsigned short f32_to_bf16(float f) {
  unsigned u = __float_as_uint(f);
  u += 0x7fffu + ((u >> 16) & 1u);
  return (unsigned short)(u >> 16);
}

__device__ __forceinline__ u16x8 cvt8(const float4& a, const float4& b) {
  u16x8 o;
  o[0] = f32_to_bf16(a.x); o[1] = f32_to_bf16(a.y);
  o[2] = f32_to_bf16(a.z); o[3] = f32_to_bf16(a.w);
  o[4] = f32_to_bf16(b.x); o[5] = f32_to_bf16(b.y);
  o[6] = f32_to_bf16(b.z); o[7] = f32_to_bf16(b.w);
  return o;
}

// async global->LDS, 16B per lane (LDS dest wave-uniform base + lane*16)
#define GLOAD_LDS16(gp, lp)                                                        \
  __builtin_amdgcn_global_load_lds((__attribute__((address_space(1))) void*)(void*)(gp), \
                                   (__attribute__((address_space(3))) void*)(void*)(lp), \
                                   16, 0, 0)

template<int V> struct IC { static constexpr int value = V; };

// ---------------- x convert: 2048 blocks x 256 thr, 8 units of 8 elems ----------------
__global__ void k_convert_x(const float* __restrict__ in, unsigned short* __restrict__ out) {
  int i0 = blockIdx.x * blockDim.x + threadIdx.x;
  #pragma unroll
  for (int it = 0; it < 8; ++it) {
    size_t i = (size_t)i0 + (size_t)it * 524288;
    const float4* p = (const float4*)in + i * 2;
    *(u16x8*)(out + i * 8) = cvt8(p[0], p[1]);
  }
}

// ---------------- combined small converts: W | Bp | A_params pack ----------------
__global__ void k_convert_small(const float* __restrict__ W, const float* __restrict__ Bp,
                                const float* __restrict__ Ap,
                                unsigned short* __restrict__ wbf, unsigned short* __restrict__ bpbf,
                                unsigned short* __restrict__ abf) {
  int b = blockIdx.x;
  if (b < 2048) {
    int i = b * 256 + threadIdx.x;
    const float4* p = (const float4*)W + (size_t)i * 2;
    *(u16x8*)(wbf + (size_t)i * 8) = cvt8(p[0], p[1]);
  } else if (b < 2176) {
    int i = (b - 2048) * 256 + threadIdx.x;
    const float4* p = (const float4*)Bp + (size_t)i * 2;
    *(u16x8*)(bpbf + (size_t)i * 8) = cvt8(p[0], p[1]);
  } else {
    int row = (b - 2176) * 256 + threadIdx.x;
    const float4* p = (const float4*)(Ap + (size_t)row * RLORA);
    u16x8 lo = cvt8(p[0], p[1]), hi2 = cvt8(p[2], p[3]), z = {0,0,0,0,0,0,0,0};
    u16x8* dst = (u16x8*)(abf + (size_t)row * 32);
    dst[0] = lo; dst[1] = hi2; dst[2] = z; dst[3] = z;
  }
}

// ---------------- inter[m][r] = sum_i xbf[m][i] * bpbf[b][r][i]  (R1-proven) ----------------
__global__ __launch_bounds__(256) void k_inter(const unsigned short* __restrict__ xbf,
                                               const unsigned short* __restrict__ bpbf,
                                               unsigned short* __restrict__ interbf) {
  const int tid  = threadIdx.x;
  const int lane = tid & 63;
  const int wv   = tid >> 6;
  const int l15  = lane & 15;
  const int hi   = lane >> 4;
  const int m0   = blockIdx.x * 64;
  const int bb   = m0 >> 11;

  floatx4 zero = {0.f, 0.f, 0.f, 0.f};
  floatx4 acc[4] = {zero, zero, zero, zero};

  const unsigned short* bpb = bpbf + (size_t)bb * (RLORA * K_TOT);
  const int kb0 = wv * 512;
  for (int kb = kb0; kb < kb0 + 512; kb += 32) {
    bf16x8 bfr = *(const bf16x8*)(bpb + (size_t)l15 * K_TOT + kb + hi * 8);
    #pragma unroll
    for (int mi = 0; mi < 4; ++mi) {
      bf16x8 afr = *(const bf16x8*)(xbf + (size_t)(m0 + mi * 16 + l15) * K_TOT + kb + hi * 8);
      acc[mi] = __builtin_amdgcn_mfma_f32_16x16x32_bf16(afr, bfr, acc[mi], 0, 0, 0);
    }
  }

  __shared__ floatx4 red[4][4][64];
  #pragma unroll
  for (int mi = 0; mi < 4; ++mi) red[wv][mi][lane] = acc[mi];
  __syncthreads();
  if (wv == 0) {
    #pragma unroll
    for (int mi = 0; mi < 4; ++mi) {
      floatx4 s = red[0][mi][lane] + red[1][mi][lane] + red[2][mi][lane] + red[3][mi][lane];
      #pragma unroll
      for (int j = 0; j < 4; ++j) {
        int m = m0 + mi * 16 + hi * 4 + j;
        interbf[(size_t)m * 32 + l15] = f32_to_bf16(s[j]);
        interbf[(size_t)m * 32 + 16 + l15] = 0;
      }
    }
  }
}

// ---------------- main GEMM: 256x256, BK=64, 8 waves — exact m201-template phase decomposition ----
// Per phase q (q=0..3 per K-tile): quadrant = rows [wm*128+q*32, +32) x all 64 cols = 2mi x 4ni x 2ks.
// B-frags (8 reads) read ONCE per K-tile in ph1; A-subtile (4 reads) fresh each phase.
// Stage exactly 1 half-tile per phase: ph1:A0(t+1)->buf^1, ph2:A1(t+1)->buf^1,
//   ph3:B0(t+2)->buf (B(buf) dead after ph1), ph4:B1(t+2)->buf.
// One vmcnt per tile, at ph4 end: vmcnt(4) drains A(t+1), leaves B(t+2) in flight.
// Peel: t=30 vmcnt(0) (no B-stage), t=31 none.
#define STAGE_A(bufi, h, tt) do {                                                      \
  GLOAD_LDS16(Ag + (h)*262144 + (tt)*64 + gOff0, AsB + ((bufi)*2+(h))*16384 + ldsB0);  \
  GLOAD_LDS16(Ag + (h)*262144 + (tt)*64 + gOff1, AsB + ((bufi)*2+(h))*16384 + ldsB1);  \
} while(0)
#define STAGE_B(bufi, h, tt) do {                                                      \
  GLOAD_LDS16(Bg + (h)*262144 + (tt)*64 + gOff0, BsB + ((bufi)*2+(h))*16384 + ldsB0);  \
  GLOAD_LDS16(Bg + (h)*262144 + (tt)*64 + gOff1, BsB + ((bufi)*2+(h))*16384 + ldsB1);  \
} while(0)
#define RDA_(B2, q, mi, ks) (*(const bf16x8*)(AsB + (B2)*32768 + aBase + (q)*4096 + (mi)*2048 + koff[ks]))
#define RDB_(B2, ni, ks)    (*(const bf16x8*)(BsB + (B2)*32768 + bBase + (ni)*2048 + koff[ks]))
#define BAR() __builtin_amdgcn_s_barrier()

__global__ __launch_bounds__(512, 2) void k_gemm(const unsigned short* __restrict__ xbf,
                                                 const unsigned short* __restrict__ wbf,
                                                 const unsigned short* __restrict__ interbf,
                                                 const unsigned short* __restrict__ abf,
                                                 const float* __restrict__ bias,
                                                 float* __restrict__ out) {
  __shared__ unsigned short As[2][2][8192];
  __shared__ unsigned short Bs[2][2][8192];
  const int tid  = threadIdx.x;
  const int lane = tid & 63;
  const int wid  = tid >> 6;     // 0..7
  const int wm   = wid >> 2;     // 0..1
  const int wn   = wid & 3;      // 0..3
  const int l15  = lane & 15;
  const int hi   = lane >> 4;
  const int swz  = l15 & 7;

  // XCD-aware bijective swizzle: grid 512 = 64 mt x 8 nt
  int bid  = blockIdx.x;
  int swzb = ((bid & 7) << 6) | (bid >> 3);
  const int mt = swzb >> 3;
  const int nt = swzb & 7;
  const int mrow0 = mt << 8;
  const int ncol0 = nt << 8;
  const int bb = mrow0 >> 11;

  const int m0 = mrow0 + wm * 128;
  const int n0 = ncol0 + wn * 64;

  const unsigned short* Ag = xbf + (size_t)mrow0 * K_TOT;
  const unsigned short* Bg = wbf + (size_t)ncol0 * K_TOT;
  char* AsB = (char*)As;
  char* BsB = (char*)Bs;

  // staging offsets (pre-swizzled source; linear LDS dest)
  const int r0    = tid >> 3;
  const int k80   = (tid & 7) ^ (r0 & 7);
  const int gOff0 = r0 * K_TOT + k80 * 8;
  const int gOff1 = gOff0 + 64 * K_TOT;
  const int ldsB0 = wid * 1024;
  const int ldsB1 = 8192 + wid * 1024;

  // fragment read bases (byte offsets)
  const int aBase = wm * 16384 + l15 * 128;
  const int bBase = (wn >> 1) * 16384 + (wn & 1) * 8192 + l15 * 128;
  int koff[2];
  koff[0] = ((0 * 4 + hi) ^ swz) * 16;
  koff[1] = ((1 * 4 + hi) ^ swz) * 16;

  floatx4 acc[8][4];
  bf16x8 bfr[4][2];   // B-frags: held for a whole K-tile
  bf16x8 af[2][2];    // A-subtile: fresh each phase

  // ---- prologue: LoRA acc-init + stage 6 half-tiles ----
  {
    bf16x8 la[8], lb[4];
    #pragma unroll
    for (int mi = 0; mi < 8; ++mi)
      la[mi] = *(const bf16x8*)(interbf + (size_t)(m0 + mi * 16 + l15) * 32 + hi * 8);
    #pragma unroll
    for (int ni = 0; ni < 4; ++ni)
      lb[ni] = *(const bf16x8*)(abf + ((size_t)bb * N_TOT + n0 + ni * 16 + l15) * 32 + hi * 8);

    // t0: A0,A1,B0,B1 -> buf0 ; t1: B0,B1 -> buf1  (A(t1) staged by t0's ph1/ph2)
    STAGE_A(0, 0, 0); STAGE_A(0, 1, 0); STAGE_B(0, 0, 0); STAGE_B(0, 1, 0);
    STAGE_B(1, 0, 1); STAGE_B(1, 1, 1);

    floatx4 z = {0.f, 0.f, 0.f, 0.f};
    #pragma unroll
    for (int mi = 0; mi < 8; ++mi)
      #pragma unroll
      for (int ni = 0; ni < 4; ++ni)
        acc[mi][ni] = __builtin_amdgcn_mfma_f32_16x16x32_bf16(la[mi], lb[ni], z, 0, 0, 0);
  }
  asm volatile("s_waitcnt vmcnt(4)" ::: "memory");   // t0's 4 halves landed; t1's B pair in flight
  BAR();

  auto tile_step = [&](int t, auto bufc, auto sac, auto sbc, auto vmc) {
    constexpr int BUF = decltype(bufc)::value;
    constexpr int SA  = decltype(sac)::value;   // stage A0,A1(t+1) -> BUF^1 at ph1,ph2
    constexpr int SB  = decltype(sbc)::value;   // stage B0,B1(t+2) -> BUF at ph3,ph4
    constexpr int VM  = decltype(vmc)::value;   // ph4-end vmcnt: 4, 0, or -1

    // ---- ph1: read B-all(8) + A-sub q0(4); stage A0(t+1); MFMA q0
    #pragma unroll
    for (int ni = 0; ni < 4; ++ni) { bfr[ni][0] = RDB_(BUF, ni, 0); bfr[ni][1] = RDB_(BUF, ni, 1); }
    #pragma unroll
    for (int mi = 0; mi < 2; ++mi) { af[mi][0] = RDA_(BUF, 0, mi, 0); af[mi][1] = RDA_(BUF, 0, mi, 1); }
    if constexpr (SA) STAGE_A(BUF ^ 1, 0, t + 1);
    BAR();
    asm volatile("s_waitcnt lgkmcnt(0)" ::: "memory");
    __builtin_amdgcn_s_setprio(1);
    #pragma unroll
    for (int mi = 0; mi < 2; ++mi)
      #pragma unroll
      for (int ni = 0; ni < 4; ++ni) {
        acc[mi][ni] = __builtin_amdgcn_mfma_f32_16x16x32_bf16(af[mi][0], bfr[ni][0], acc[mi][ni], 0, 0, 0);
        acc[mi][ni] = __builtin_amdgcn_mfma_f32_16x16x32_bf16(af[mi][1], bfr[ni][1], acc[mi][ni], 0, 0, 0);
      }
    __builtin_amdgcn_s_setprio(0);
    BAR();

    // ---- ph2: read A-sub q1; stage A1(t+1); MFMA q1
    #pragma unroll
    for (int mi = 0; mi < 2; ++mi) { af[mi][0] = RDA_(BUF, 1, mi, 0); af[mi][1] = RDA_(BUF, 1, mi, 1); }
    if constexpr (SA) STAGE_A(BUF ^ 1, 1, t + 1);
    BAR();
    asm volatile("s_waitcnt lgkmcnt(0)" ::: "memory");
    __builtin_amdgcn_s_setprio(1);
    #pragma unroll
    for (int mi = 0; mi < 2; ++mi)
      #pragma unroll
      for (int ni = 0; ni < 4; ++ni) {
        acc[2+mi][ni] = __builtin_amdgcn_mfma_f32_16x16x32_bf16(af[mi][0], bfr[ni][0], acc[2+mi][ni], 0, 0, 0);
        acc[2+mi][ni] = __builtin_amdgcn_mfma_f32_16x16x32_bf16(af[mi][1], bfr[ni][1], acc[2+mi][ni], 0, 0, 0);
      }
    __builtin_amdgcn_s_setprio(0);
    BAR();

    // ---- ph3: read A-sub q2; stage B0(t+2) (B(buf) dead after ph1); MFMA q2
    #pragma unroll
    for (int mi = 0; mi < 2; ++mi) { af[mi][0] = RDA_(BUF, 2, mi, 0); af[mi][1] = RDA_(BUF, 2, mi, 1); }
    if constexpr (SB) STAGE_B(BUF, 0, t + 2);
    BAR();
    asm volatile("s_waitcnt lgkmcnt(0)" ::: "memory");
    __builtin_amdgcn_s_setprio(1);
    #pragma unroll
    for (int mi = 0; mi < 2; ++mi)
      #pragma unroll
      for (int ni = 0; ni < 4; ++ni) {
        acc[4+mi][ni] = __builtin_amdgcn_mfma_f32_16x16x32_bf16(af[mi][0], bfr[ni][0], acc[4+mi][ni], 0, 0, 0);
        acc[4+mi][ni] = __builtin_amdgcn_mfma_f32_16x16x32_bf16(af[mi][1], bfr[ni][1], acc[4+mi][ni], 0, 0, 0);
      }
    __builtin_amdgcn_s_setprio(0);
    BAR();

    // ---- ph4: read A-sub q3; stage B1(t+2); MFMA q3; vmcnt at end
    #pragma unroll
    for (int mi = 0; mi < 2; ++mi) { af[mi][0] = RDA_(BUF, 3, mi, 0); af[mi][1] = RDA_(BUF, 3, mi, 1); }
    if constexpr (SB) STAGE_B(BUF, 1, t + 2);
    BAR();
    asm volatile("s_waitcnt lgkmcnt(0)" ::: "memory");
    __builtin_amdgcn_s_setprio(1);
    #pragma unroll
    for (int mi = 0; mi < 2; ++mi)
      #pragma unroll
      for (int ni = 0; ni < 4; ++ni) {
        acc[6+mi][ni] = __builtin_amdgcn_mfma_f32_16x16x32_bf16(af[mi][0], bfr[ni][0], acc[6+mi][ni], 0, 0, 0);
        acc[6+mi][ni] = __builtin_amdgcn_mfma_f32_16x16x32_bf16(af[mi][1], bfr[ni][1], acc[6+mi][ni], 0, 0, 0);
      }
    __builtin_amdgcn_s_setprio(0);
    if constexpr (VM == 4)      asm volatile("s_waitcnt vmcnt(4)" ::: "memory");
    else if constexpr (VM == 0) asm volatile("s_waitcnt vmcnt(0)" ::: "memory");
    BAR();
  };

  for (int t = 0; t < NT - 2; t += 2) {
    tile_step(t,     IC<0>{}, IC<1>{}, IC<1>{}, IC<4>{});
    tile_step(t + 1, IC<1>{}, IC<1>{}, IC<1>{}, IC<4>{});
  }
  tile_step(NT - 2, IC<0>{}, IC<1>{}, IC<0>{}, IC<0>{});
  tile_step(NT - 1, IC<1>{}, IC<0>{}, IC<0>{}, IC<-1>{});

  // ---- epilogue: + bias, store f32 ----
  #pragma unroll
  for (int ni = 0; ni < 4; ++ni) {
    int col = n0 + ni * 16 + l15;
    float bv = bias[col];
    #pragma unroll
    for (int mi = 0; mi < 8; ++mi) {
      int r = m0 + mi * 16 + hi * 4;
      #pragma unroll
      for (int j = 0; j < 4; ++j)
        out[(size_t)(r + j) * N_TOT + col] = acc[mi][ni][j] + bv;
    }
  }
}

// ---------------- launcher ----------------
extern "C" void kernel_launch(void* const* d_in, const int* in_sizes, int n_in,
                              void* d_out, int out_size, void* d_ws, size_t ws_size,
                              hipStream_t stream) {
  const float* x    = (const float*)d_in[0];   // [8,2048,2048]
  const float* Ap   = (const float*)d_in[1];   // [8,2048,16]
  const float* Bp   = (const float*)d_in[2];   // [8,16,2048]
  const float* W    = (const float*)d_in[3];   // [2048,2048]
  const float* bias = (const float*)d_in[4];   // [2048]
  float* out = (float*)d_out;

  char* ws = (char*)d_ws;
  unsigned short* xbf     = (unsigned short*)(ws);                        // 64 MiB
  unsigned short* wbf     = (unsigned short*)(ws + 67108864);             // 8 MiB
  unsigned short* abf     = (unsigned short*)(ws + 67108864 + 8388608);   // 1 MiB
  unsigned short* bpbf    = (unsigned short*)(ws + 67108864 + 8388608 + 1048576);          // 0.5 MiB
  unsigned short* interbf = (unsigned short*)(ws + 67108864 + 8388608 + 1048576 + 524288); // 1 MiB

  k_convert_small<<<dim3(2240), dim3(256), 0, stream>>>(W, Bp, Ap, wbf, bpbf, abf);
  k_convert_x<<<dim3(2048), dim3(256), 0, stream>>>(x, xbf);
  k_inter<<<dim3(256), dim3(256), 0, stream>>>(xbf, bpbf, interbf);
  k_gemm<<<dim3(512), dim3(512), 0, stream>>>(xbf, wbf, interbf, abf, bias, out);
}

// Round 7
// 192.514 us; speedup vs baseline: 1.2819x; 1.0264x over previous
//
#include <hip/hip_runtime.h>
#include <cstdint>
#include <cstddef>

// ---------------- types ----------------
typedef __attribute__((ext_vector_type(4))) float  floatx4;
typedef __attribute__((ext_vector_type(8))) __bf16 bf16x8;
typedef __attribute__((ext_vector_type(8))) unsigned short u16x8;

#define M_TOT 16384   // B*S
#define N_TOT 2048    // D_OUT
#define K_TOT 2048    // D_IN
#define NBATCH 8
#define RLORA 16
#define NT 32         // K tiles of 64

// f32 -> bf16 round-to-nearest-even
__device__ __forceinline__ unsigned short f32_to_bf16(float f) {
  unsigned u = __float_as_uint(f);
  u += 0x7fffu + ((u >> 16) & 1u);
  return (unsigned short)(u >> 16);
}

__device__ __forceinline__ u16x8 cvt8(const float4& a, const float4& b) {
  u16x8 o;
  o[0] = f32_to_bf16(a.x); o[1] = f32_to_bf16(a.y);
  o[2] = f32_to_bf16(a.z); o[3] = f32_to_bf16(a.w);
  o[4] = f32_to_bf16(b.x); o[5] = f32_to_bf16(b.y);
  o[6] = f32_to_bf16(b.z); o[7] = f32_to_bf16(b.w);
  return o;
}

// async global->LDS, 16B per lane (LDS dest wave-uniform base + lane*16)
#define GLOAD_LDS16(gp, lp)                                                        \
  __builtin_amdgcn_global_load_lds((__attribute__((address_space(1))) void*)(void*)(gp), \
                                   (__attribute__((address_space(3))) void*)(void*)(lp), \
                                   16, 0, 0)

template<int V> struct IC { static constexpr int value = V; };

// ---------------- combined small converts: W (2048 blocks) | A_params pack (64 blocks) ----------------
__global__ void k_convert_small(const float* __restrict__ W, const float* __restrict__ Ap,
                                unsigned short* __restrict__ wbf, unsigned short* __restrict__ abf) {
  int b = blockIdx.x;
  if (b < 2048) {
    int i = b * 256 + threadIdx.x;
    const float4* p = (const float4*)W + (size_t)i * 2;
    *(u16x8*)(wbf + (size_t)i * 8) = cvt8(p[0], p[1]);
  } else {
    int row = (b - 2048) * 256 + threadIdx.x;
    const float4* p = (const float4*)(Ap + (size_t)row * RLORA);
    u16x8 lo = cvt8(p[0], p[1]), hi2 = cvt8(p[2], p[3]), z = {0,0,0,0,0,0,0,0};
    u16x8* dst = (u16x8*)(abf + (size_t)row * 32);
    dst[0] = lo; dst[1] = hi2; dst[2] = z; dst[3] = z;
  }
}

// ---------------- fused: xbf = bf16(x) AND inter = x @ Bp^T ----------------
// 1024 blocks x 256 thr; block = 16 rows (one m-tile); 4 waves split K (512 each).
// The f32 x load IS the MFMA A-fragment (row=l15, k=hi*8+j): per row, 4 hi-lanes cover the
// full 128B cache line. Bp (2 MiB f32) is L2-resident. Converts in-reg, writes xbf on the way.
__global__ __launch_bounds__(256) void k_xinter(const float* __restrict__ x,
                                                const float* __restrict__ Bp,
                                                unsigned short* __restrict__ xbf,
                                                unsigned short* __restrict__ interbf) {
  const int tid  = threadIdx.x;
  const int lane = tid & 63;
  const int wv   = tid >> 6;
  const int l15  = lane & 15;
  const int hi   = lane >> 4;
  const int m0   = blockIdx.x * 16;
  const int bb   = m0 >> 11;

  floatx4 acc = {0.f, 0.f, 0.f, 0.f};
  const float* bpb = Bp + (size_t)bb * (RLORA * K_TOT);
  const size_t xrow = (size_t)(m0 + l15) * K_TOT;
  const size_t brow = (size_t)l15 * K_TOT;
  const int kb0 = wv * 512;
  for (int kb = kb0; kb < kb0 + 512; kb += 32) {
    const float* xp = x + xrow + kb + hi * 8;
    u16x8 ao = cvt8(*(const float4*)xp, *(const float4*)(xp + 4));
    *(u16x8*)(xbf + xrow + kb + hi * 8) = ao;
    const float* bpp = bpb + brow + kb + hi * 8;
    u16x8 bo = cvt8(*(const float4*)bpp, *(const float4*)(bpp + 4));
    acc = __builtin_amdgcn_mfma_f32_16x16x32_bf16(*(bf16x8*)&ao, *(bf16x8*)&bo, acc, 0, 0, 0);
  }

  __shared__ floatx4 red[4][64];
  red[wv][lane] = acc;
  __syncthreads();
  if (wv == 0) {
    floatx4 s = red[0][lane] + red[1][lane] + red[2][lane] + red[3][lane];
    #pragma unroll
    for (int j = 0; j < 4; ++j) {
      int m = m0 + hi * 4 + j;          // C/D layout: row = hi*4+j, col = l15 = r
      interbf[(size_t)m * 32 + l15] = f32_to_bf16(s[j]);
      interbf[(size_t)m * 32 + 16 + l15] = 0;
    }
  }
}

// ---------------- main GEMM: 256x256, BK=64, 8 waves, 8-phase (R6 structure) ----------------
// CHANGE vs R6: no forced lgkmcnt(0) before MFMA clusters — compiler inserts fine-grained
// per-operand counted lgkm waits, letting later MFMAs' ds_reads drain under earlier MFMAs.
#define STAGE_A(bufi, h, tt) do {                                                      \
  GLOAD_LDS16(Ag + (h)*262144 + (tt)*64 + gOff0, AsB + ((bufi)*2+(h))*16384 + ldsB0);  \
  GLOAD_LDS16(Ag + (h)*262144 + (tt)*64 + gOff1, AsB + ((bufi)*2+(h))*16384 + ldsB1);  \
} while(0)
#define STAGE_B(bufi, h, tt) do {                                                      \
  GLOAD_LDS16(Bg + (h)*262144 + (tt)*64 + gOff0, BsB + ((bufi)*2+(h))*16384 + ldsB0);  \
  GLOAD_LDS16(Bg + (h)*262144 + (tt)*64 + gOff1, BsB + ((bufi)*2+(h))*16384 + ldsB1);  \
} while(0)
#define RDA_(B2, q, mi, ks) (*(const bf16x8*)(AsB + (B2)*32768 + aBase + (q)*4096 + (mi)*2048 + koff[ks]))
#define RDB_(B2, ni, ks)    (*(const bf16x8*)(BsB + (B2)*32768 + bBase + (ni)*2048 + koff[ks]))
#define BAR() __builtin_amdgcn_s_barrier()

__global__ __launch_bounds__(512, 2) void k_gemm(const unsigned short* __restrict__ xbf,
                                                 const unsigned short* __restrict__ wbf,
                                                 const unsigned short* __restrict__ interbf,
                                                 const unsigned short* __restrict__ abf,
                                                 const float* __restrict__ bias,
                                                 float* __restrict__ out) {
  __shared__ unsigned short As[2][2][8192];
  __shared__ unsigned short Bs[2][2][8192];
  const int tid  = threadIdx.x;
  const int lane = tid & 63;
  const int wid  = tid >> 6;     // 0..7
  const int wm   = wid >> 2;     // 0..1
  const int wn   = wid & 3;      // 0..3
  const int l15  = lane & 15;
  const int hi   = lane >> 4;
  const int swz  = l15 & 7;

  // XCD-aware bijective swizzle: grid 512 = 64 mt x 8 nt
  int bid  = blockIdx.x;
  int swzb = ((bid & 7) << 6) | (bid >> 3);
  const int mt = swzb >> 3;
  const int nt = swzb & 7;
  const int mrow0 = mt << 8;
  const int ncol0 = nt << 8;
  const int bb = mrow0 >> 11;

  const int m0 = mrow0 + wm * 128;
  const int n0 = ncol0 + wn * 64;

  const unsigned short* Ag = xbf + (size_t)mrow0 * K_TOT;
  const unsigned short* Bg = wbf + (size_t)ncol0 * K_TOT;
  char* AsB = (char*)As;
  char* BsB = (char*)Bs;

  // staging offsets (pre-swizzled source; linear LDS dest)
  const int r0    = tid >> 3;
  const int k80   = (tid & 7) ^ (r0 & 7);
  const int gOff0 = r0 * K_TOT + k80 * 8;
  const int gOff1 = gOff0 + 64 * K_TOT;
  const int ldsB0 = wid * 1024;
  const int ldsB1 = 8192 + wid * 1024;

  // fragment read bases (byte offsets)
  const int aBase = wm * 16384 + l15 * 128;
  const int bBase = (wn >> 1) * 16384 + (wn & 1) * 8192 + l15 * 128;
  int koff[2];
  koff[0] = ((0 * 4 + hi) ^ swz) * 16;
  koff[1] = ((1 * 4 + hi) ^ swz) * 16;

  floatx4 acc[8][4];
  bf16x8 bfr[4][2];   // B-frags: held for a whole K-tile
  bf16x8 af[2][2];    // A-subtile: fresh each phase

  // ---- prologue: LoRA acc-init + stage 6 half-tiles ----
  {
    bf16x8 la[8], lb[4];
    #pragma unroll
    for (int mi = 0; mi < 8; ++mi)
      la[mi] = *(const bf16x8*)(interbf + (size_t)(m0 + mi * 16 + l15) * 32 + hi * 8);
    #pragma unroll
    for (int ni = 0; ni < 4; ++ni)
      lb[ni] = *(const bf16x8*)(abf + ((size_t)bb * N_TOT + n0 + ni * 16 + l15) * 32 + hi * 8);

    STAGE_A(0, 0, 0); STAGE_A(0, 1, 0); STAGE_B(0, 0, 0); STAGE_B(0, 1, 0);
    STAGE_B(1, 0, 1); STAGE_B(1, 1, 1);

    floatx4 z = {0.f, 0.f, 0.f, 0.f};
    #pragma unroll
    for (int mi = 0; mi < 8; ++mi)
      #pragma unroll
      for (int ni = 0; ni < 4; ++ni)
        acc[mi][ni] = __builtin_amdgcn_mfma_f32_16x16x32_bf16(la[mi], lb[ni], z, 0, 0, 0);
  }
  asm volatile("s_waitcnt vmcnt(4)" ::: "memory");   // t0's 4 halves landed; t1's B pair in flight
  BAR();

  auto tile_step = [&](int t, auto bufc, auto sac, auto sbc, auto vmc) {
    constexpr int BUF = decltype(bufc)::value;
    constexpr int SA  = decltype(sac)::value;   // stage A0,A1(t+1) -> BUF^1 at ph1,ph2
    constexpr int SB  = decltype(sbc)::value;   // stage B0,B1(t+2) -> BUF at ph3,ph4
    constexpr int VM  = decltype(vmc)::value;   // ph4-end vmcnt: 4, 0, or -1

    // ---- ph1: read B-all(8) + A-sub q0(4); stage A0(t+1); MFMA q0
    #pragma unroll
    for (int ni = 0; ni < 4; ++ni) { bfr[ni][0] = RDB_(BUF, ni, 0); bfr[ni][1] = RDB_(BUF, ni, 1); }
    #pragma unroll
    for (int mi = 0; mi < 2; ++mi) { af[mi][0] = RDA_(BUF, 0, mi, 0); af[mi][1] = RDA_(BUF, 0, mi, 1); }
    if constexpr (SA) STAGE_A(BUF ^ 1, 0, t + 1);
    BAR();
    __builtin_amdgcn_s_setprio(1);
    #pragma unroll
    for (int mi = 0; mi < 2; ++mi)
      #pragma unroll
      for (int ni = 0; ni < 4; ++ni) {
        acc[mi][ni] = __builtin_amdgcn_mfma_f32_16x16x32_bf16(af[mi][0], bfr[ni][0], acc[mi][ni], 0, 0, 0);
        acc[mi][ni] = __builtin_amdgcn_mfma_f32_16x16x32_bf16(af[mi][1], bfr[ni][1], acc[mi][ni], 0, 0, 0);
      }
    __builtin_amdgcn_s_setprio(0);
    BAR();

    // ---- ph2: read A-sub q1; stage A1(t+1); MFMA q1
    #pragma unroll
    for (int mi = 0; mi < 2; ++mi) { af[mi][0] = RDA_(BUF, 1, mi, 0); af[mi][1] = RDA_(BUF, 1, mi, 1); }
    if constexpr (SA) STAGE_A(BUF ^ 1, 1, t + 1);
    BAR();
    __builtin_amdgcn_s_setprio(1);
    #pragma unroll
    for (int mi = 0; mi < 2; ++mi)
      #pragma unroll
      for (int ni = 0; ni < 4; ++ni) {
        acc[2+mi][ni] = __builtin_amdgcn_mfma_f32_16x16x32_bf16(af[mi][0], bfr[ni][0], acc[2+mi][ni], 0, 0, 0);
        acc[2+mi][ni] = __builtin_amdgcn_mfma_f32_16x16x32_bf16(af[mi][1], bfr[ni][1], acc[2+mi][ni], 0, 0, 0);
      }
    __builtin_amdgcn_s_setprio(0);
    BAR();

    // ---- ph3: read A-sub q2; stage B0(t+2) (B(buf) dead after ph1); MFMA q2
    #pragma unroll
    for (int mi = 0; mi < 2; ++mi) { af[mi][0] = RDA_(BUF, 2, mi, 0); af[mi][1] = RDA_(BUF, 2, mi, 1); }
    if constexpr (SB) STAGE_B(BUF, 0, t + 2);
    BAR();
    __builtin_amdgcn_s_setprio(1);
    #pragma unroll
    for (int mi = 0; mi < 2; ++mi)
      #pragma unroll
      for (int ni = 0; ni < 4; ++ni) {
        acc[4+mi][ni] = __builtin_amdgcn_mfma_f32_16x16x32_bf16(af[mi][0], bfr[ni][0], acc[4+mi][ni], 0, 0, 0);
        acc[4+mi][ni] = __builtin_amdgcn_mfma_f32_16x16x32_bf16(af[mi][1], bfr[ni][1], acc[4+mi][ni], 0, 0, 0);
      }
    __builtin_amdgcn_s_setprio(0);
    BAR();

    // ---- ph4: read A-sub q3; stage B1(t+2); MFMA q3; vmcnt at end
    #pragma unroll
    for (int mi = 0; mi < 2; ++mi) { af[mi][0] = RDA_(BUF, 3, mi, 0); af[mi][1] = RDA_(BUF, 3, mi, 1); }
    if constexpr (SB) STAGE_B(BUF, 1, t + 2);
    BAR();
    __builtin_amdgcn_s_setprio(1);
    #pragma unroll
    for (int mi = 0; mi < 2; ++mi)
      #pragma unroll
      for (int ni = 0; ni < 4; ++ni) {
        acc[6+mi][ni] = __builtin_amdgcn_mfma_f32_16x16x32_bf16(af[mi][0], bfr[ni][0], acc[6+mi][ni], 0, 0, 0);
        acc[6+mi][ni] = __builtin_amdgcn_mfma_f32_16x16x32_bf16(af[mi][1], bfr[ni][1], acc[6+mi][ni], 0, 0, 0);
      }
    __builtin_amdgcn_s_setprio(0);
    if constexpr (VM == 4)      asm volatile("s_waitcnt vmcnt(4)" ::: "memory");
    else if constexpr (VM == 0) asm volatile("s_waitcnt vmcnt(0)" ::: "memory");
    BAR();
  };

  for (int t = 0; t < NT - 2; t += 2) {
    tile_step(t,     IC<0>{}, IC<1>{}, IC<1>{}, IC<4>{});
    tile_step(t + 1, IC<1>{}, IC<1>{}, IC<1>{}, IC<4>{});
  }
  tile_step(NT - 2, IC<0>{}, IC<1>{}, IC<0>{}, IC<0>{});
  tile_step(NT - 1, IC<1>{}, IC<0>{}, IC<0>{}, IC<-1>{});

  // ---- epilogue: + bias, store f32 ----
  #pragma unroll
  for (int ni = 0; ni < 4; ++ni) {
    int col = n0 + ni * 16 + l15;
    float bv = bias[col];
    #pragma unroll
    for (int mi = 0; mi < 8; ++mi) {
      int r = m0 + mi * 16 + hi * 4;
      #pragma unroll
      for (int j = 0; j < 4; ++j)
        out[(size_t)(r + j) * N_TOT + col] = acc[mi][ni][j] + bv;
    }
  }
}

// ---------------- launcher ----------------
extern "C" void kernel_launch(void* const* d_in, const int* in_sizes, int n_in,
                              void* d_out, int out_size, void* d_ws, size_t ws_size,
                              hipStream_t stream) {
  const float* x    = (const float*)d_in[0];   // [8,2048,2048]
  const float* Ap   = (const float*)d_in[1];   // [8,2048,16]
  const float* Bp   = (const float*)d_in[2];   // [8,16,2048]
  const float* W    = (const float*)d_in[3];   // [2048,2048]
  const float* bias = (const float*)d_in[4];   // [2048]
  float* out = (float*)d_out;

  char* ws = (char*)d_ws;
  unsigned short* xbf     = (unsigned short*)(ws);                        // 64 MiB
  unsigned short* wbf     = (unsigned short*)(ws + 67108864);             // 8 MiB
  unsigned short* abf     = (unsigned short*)(ws + 67108864 + 8388608);   // 1 MiB
  unsigned short* interbf = (unsigned short*)(ws + 67108864 + 8388608 + 1048576); // 1 MiB

  k_convert_small<<<dim3(2112), dim3(256), 0, stream>>>(W, Ap, wbf, abf);
  k_xinter<<<dim3(1024), dim3(256), 0, stream>>>(x, Bp, xbf, interbf);
  k_gemm<<<dim3(512), dim3(512), 0, stream>>>(xbf, wbf, interbf, abf, bias, out);
}